// Round 2
// baseline (13217.297 us; speedup 1.0000x reference)
//
#include <hip/hip_runtime.h>
#include <stdint.h>
#include <stddef.h>

typedef __attribute__((ext_vector_type(8))) short bf16x8;
typedef __attribute__((ext_vector_type(4))) float f32x4;

#define NBLK 128
#define NTHR 256
#define S_LEN 512
#define HD   1024
#define IDIM 512

#define MFMA16 __builtin_amdgcn_mfma_f32_16x16x32_bf16

__device__ __forceinline__ float bf2f(uint16_t u){
  union { uint32_t i; float f; } v; v.i = ((uint32_t)u) << 16; return v.f;
}
__device__ __forceinline__ uint16_t f2bf(float f){
  union { float f; uint32_t i; } v; v.f = f;
  uint32_t r = v.i + 0x7fffu + ((v.i >> 16) & 1u);   // round-nearest-even
  return (uint16_t)(r >> 16);
}
__device__ __forceinline__ float sigm(float x){ return 1.0f / (1.0f + __expf(-x)); }
__device__ __forceinline__ float tanh_(float x){
  float t = fminf(fmaxf(2.0f * x, -30.0f), 30.0f);
  float e = __expf(t);
  return (e - 1.0f) / (e + 1.0f);
}

// Split 8 consecutive fp32 into bf16 hi + bf16 lo (residual) fragments.
__device__ __forceinline__ void split8(const float* p, bf16x8& hi8, bf16x8& lo8){
  const float4 a = *(const float4*)p;
  const float4 b = *(const float4*)(p + 4);
  float v[8] = {a.x, a.y, a.z, a.w, b.x, b.y, b.z, b.w};
  #pragma unroll
  for (int j = 0; j < 8; ++j){
    uint16_t h = f2bf(v[j]);
    hi8[j] = (short)h;
    lo8[j] = (short)f2bf(v[j] - bf2f(h));
  }
}

// Persistent LSTM. 128 blocks; block f owns h-cols [8f,8f+8).
// Gate tiles (N=16): tile0 = [H1|H2] (forget|input), tile1 = [H3|H4] (cand|out).
// K split across 4 waves (h:256 each, x:128 each); weights live in VGPRs as
// bf16 hi+lo pairs; A*W done with 3 MFMAs (Ahi*Whi + Alo*Whi + Ahi*Wlo) for
// ~fp32-grade accuracy. x-phase runs before the grid-barrier wait (hidden).
__global__ void __launch_bounds__(NTHR, 1) lstm_persist(
    const float* __restrict__ x,
    const float* __restrict__ X1, const float* __restrict__ H1, const float* __restrict__ b1,
    const float* __restrict__ X2, const float* __restrict__ H2, const float* __restrict__ b2,
    const float* __restrict__ X3, const float* __restrict__ H3, const float* __restrict__ b3,
    const float* __restrict__ X4, const float* __restrict__ H4, const float* __restrict__ b4,
    float* __restrict__ out, uint16_t* hbhi, uint16_t* hblo, int* arrive)
{
  __shared__ float part[4][64][36];   // stride 36: quad row-step 4*36 ≡ 16 (mod 32) → 2-way only
  const int tid  = threadIdx.x;
  const int w    = tid >> 6;          // wave 0..3
  const int L    = tid & 63;
  const int c    = L & 15;            // MFMA n / A-row-in-tile
  const int quad = L >> 4;
  const int cc   = c & 7;
  const int f    = blockIdx.x;
  const int colh = f * 8 + cc;        // owned h-column
  const bool hiHalf = (c >= 8);

  const float* W0 = hiHalf ? H2 : H1;
  const float* W1 = hiHalf ? H4 : H3;
  const float* V0 = hiHalf ? X2 : X1;
  const float* V1 = hiHalf ? X4 : X3;
  const float bias0 = (hiHalf ? b2 : b1)[colh];
  const float bias1 = (hiHalf ? b4 : b3)[colh];

  // --- one-time: weight fragments (B layout: n = lane&15, k = quad*8 + j) ---
  bf16x8 BhH0[8], BhL0[8], BhH1[8], BhL1[8];
  #pragma unroll
  for (int kk = 0; kk < 8; ++kk){
    const int kb = w*256 + kk*32 + quad*8;
    bf16x8 h0, l0, h1, l1;
    #pragma unroll
    for (int j = 0; j < 8; ++j){
      float w0 = W0[(size_t)(kb + j)*HD + colh];
      uint16_t a = f2bf(w0); h0[j] = (short)a; l0[j] = (short)f2bf(w0 - bf2f(a));
      float w1 = W1[(size_t)(kb + j)*HD + colh];
      uint16_t b_ = f2bf(w1); h1[j] = (short)b_; l1[j] = (short)f2bf(w1 - bf2f(b_));
    }
    BhH0[kk] = h0; BhL0[kk] = l0; BhH1[kk] = h1; BhL1[kk] = l1;
  }
  bf16x8 BxH0[4], BxL0[4], BxH1[4], BxL1[4];
  #pragma unroll
  for (int kk = 0; kk < 4; ++kk){
    const int kb = w*128 + kk*32 + quad*8;
    bf16x8 h0, l0, h1, l1;
    #pragma unroll
    for (int j = 0; j < 8; ++j){
      float w0 = V0[(size_t)(kb + j)*HD + colh];
      uint16_t a = f2bf(w0); h0[j] = (short)a; l0[j] = (short)f2bf(w0 - bf2f(a));
      float w1 = V1[(size_t)(kb + j)*HD + colh];
      uint16_t b_ = f2bf(w1); h1[j] = (short)b_; l1[j] = (short)f2bf(w1 - bf2f(b_));
    }
    BxH0[kk] = h0; BxL0[kk] = l0; BxH1[kk] = h1; BxL1[kk] = l1;
  }

  float cst[4] = {0.f, 0.f, 0.f, 0.f};

  #pragma unroll 1
  for (int t = 0; t < S_LEN; ++t){
    const int p = t & 1;
    f32x4 acc0[4], acc1[4];
    #pragma unroll
    for (int m = 0; m < 4; ++m){
      acc0[m] = (f32x4){0.f,0.f,0.f,0.f};
      acc1[m] = (f32x4){0.f,0.f,0.f,0.f};
    }

    // ---- x-phase: x_t @ Xcat slice (independent of h; hides under the wait) ----
    #pragma unroll
    for (int kk = 0; kk < 4; ++kk){
      #pragma unroll
      for (int m = 0; m < 4; ++m){
        const float* xp = x + ((size_t)(16*m + c)*S_LEN + t)*IDIM + w*128 + kk*32 + quad*8;
        bf16x8 Ah, Al; split8(xp, Ah, Al);
        acc0[m] = MFMA16(Ah, BxH0[kk], acc0[m], 0, 0, 0);
        acc0[m] = MFMA16(Al, BxH0[kk], acc0[m], 0, 0, 0);
        acc0[m] = MFMA16(Ah, BxL0[kk], acc0[m], 0, 0, 0);
        acc1[m] = MFMA16(Ah, BxH1[kk], acc1[m], 0, 0, 0);
        acc1[m] = MFMA16(Al, BxH1[kk], acc1[m], 0, 0, 0);
        acc1[m] = MFMA16(Ah, BxL1[kk], acc1[m], 0, 0, 0);
      }
    }

    // ---- wait for h_t (produced at end of step t-1 by all blocks) ----
    if (t > 0){
      __syncthreads();
      if (tid == 0){
        while (__hip_atomic_load(&arrive[t-1], __ATOMIC_RELAXED, __HIP_MEMORY_SCOPE_AGENT) < NBLK)
          __builtin_amdgcn_s_sleep(1);
        __threadfence();   // acquire: invalidate L1/L2 before reading new h
      }
      __syncthreads();
    }

    // ---- h-phase: h_t @ Hcat slice (pre-split hi/lo bf16, zero conversion) ----
    const uint16_t* hbH = hbhi + (size_t)p * (64*HD);
    const uint16_t* hbL = hblo + (size_t)p * (64*HD);
    #pragma unroll
    for (int kk = 0; kk < 8; ++kk){
      #pragma unroll
      for (int m = 0; m < 4; ++m){
        const size_t off = (size_t)(16*m + c)*HD + w*256 + kk*32 + quad*8;
        bf16x8 Ah = *(const bf16x8*)(hbH + off);
        bf16x8 Al = *(const bf16x8*)(hbL + off);
        acc0[m] = MFMA16(Ah, BhH0[kk], acc0[m], 0, 0, 0);
        acc0[m] = MFMA16(Al, BhH0[kk], acc0[m], 0, 0, 0);
        acc0[m] = MFMA16(Ah, BhL0[kk], acc0[m], 0, 0, 0);
        acc1[m] = MFMA16(Ah, BhH1[kk], acc1[m], 0, 0, 0);
        acc1[m] = MFMA16(Al, BhH1[kk], acc1[m], 0, 0, 0);
        acc1[m] = MFMA16(Ah, BhL1[kk], acc1[m], 0, 0, 0);
      }
    }

    // ---- stash partials (C/D: col = lane&15, row = quad*4 + reg) ----
    #pragma unroll
    for (int m = 0; m < 4; ++m){
      #pragma unroll
      for (int r = 0; r < 4; ++r){
        part[w][16*m + quad*4 + r][c]      = acc0[m][r];
        part[w][16*m + quad*4 + r][16 + c] = acc1[m][r];
      }
    }
    __syncthreads();

    // ---- cross-wave K-reduction; wave w handles batch rows [16w,16w+16) ----
    float g0[4], g1[4];
    #pragma unroll
    for (int r = 0; r < 4; ++r){
      const int row = 16*w + quad*4 + r;
      float a = bias0, b = bias1;
      #pragma unroll
      for (int ww = 0; ww < 4; ++ww){
        a += part[ww][row][c];
        b += part[ww][row][16 + c];
      }
      g0[r] = a; g1[r] = b;
    }

    // ---- gates (lane c<8 holds forget/cand; partner c+8 holds input/output) ----
    uint16_t* hwH = hbhi + (size_t)(p^1) * (64*HD);
    uint16_t* hwL = hblo + (size_t)(p^1) * (64*HD);
    float hv[4];
    #pragma unroll
    for (int r = 0; r < 4; ++r){
      float gf = g0[r];
      float gi = __shfl_xor(g0[r], 8, 64);
      float gc = g1[r];
      float go = __shfl_xor(g1[r], 8, 64);
      float cn = cst[r] * sigm(gf) + sigm(gi) * tanh_(gc);
      cst[r] = cn;
      hv[r] = tanh_(cn) * sigm(go);
    }
    if (!hiHalf){
      #pragma unroll
      for (int r = 0; r < 4; ++r){
        const int batch = 16*w + quad*4 + r;
        __builtin_nontemporal_store(hv[r], &out[(size_t)(batch*S_LEN + t)*HD + colh]);
        uint16_t hh = f2bf(hv[r]);
        hwH[(size_t)batch*HD + colh] = hh;
        hwL[(size_t)batch*HD + colh] = f2bf(hv[r] - bf2f(hh));
      }
    }

    // ---- signal: all block stores drained (syncthreads) → L2 writeback → count ----
    __syncthreads();
    if (tid == 0){
      __threadfence();   // release: wbl2 so other XCDs see our h hi/lo stores
      __hip_atomic_fetch_add(&arrive[t], 1, __ATOMIC_RELAXED, __HIP_MEMORY_SCOPE_AGENT);
    }
  }
}

extern "C" void kernel_launch(void* const* d_in, const int* in_sizes, int n_in,
                              void* d_out, int out_size, void* d_ws, size_t ws_size,
                              hipStream_t stream) {
  const float* x  = (const float*)d_in[0];
  const float* X1 = (const float*)d_in[1];
  const float* H1 = (const float*)d_in[2];
  const float* b1 = (const float*)d_in[3];
  const float* X2 = (const float*)d_in[4];
  const float* H2 = (const float*)d_in[5];
  const float* b2 = (const float*)d_in[6];
  const float* X3 = (const float*)d_in[7];
  const float* H3 = (const float*)d_in[8];
  const float* b3 = (const float*)d_in[9];
  const float* X4 = (const float*)d_in[10];
  const float* H4 = (const float*)d_in[11];
  const float* b4 = (const float*)d_in[12];
  float* out = (float*)d_out;

  // ws: hbhi [2][64][1024] bf16 (262144 B) | hblo same (262144 B) | arrive[512] (2048 B)
  uint16_t* hbhi = (uint16_t*)d_ws;
  uint16_t* hblo = (uint16_t*)((char*)d_ws + 262144);
  int* arrive    = (int*)((char*)d_ws + 524288);
  hipMemsetAsync(d_ws, 0, 526336, stream);   // h0 = 0 (hi/lo), counters = 0

  hipLaunchKernelGGL(lstm_persist, dim3(NBLK), dim3(NTHR), 0, stream,
                     x, X1, H1, b1, X2, H2, b2, X3, H3, b3, X4, H4, b4,
                     out, hbhi, hblo, arrive);
}

// Round 3
// 13201.131 us; speedup vs baseline: 1.0012x; 1.0012x over previous
//
#include <hip/hip_runtime.h>
#include <stdint.h>
#include <stddef.h>

typedef __attribute__((ext_vector_type(8))) short bf16x8;
typedef __attribute__((ext_vector_type(4))) float f32x4;

#define NBLK 128
#define NTHR 256
#define S_LEN 512
#define HD   1024
#define IDIM 512

#define MFMA16 __builtin_amdgcn_mfma_f32_16x16x32_bf16

__device__ __forceinline__ float bf2f(uint16_t u){
  union { uint32_t i; float f; } v; v.i = ((uint32_t)u) << 16; return v.f;
}
__device__ __forceinline__ uint16_t f2bf(float f){
  union { float f; uint32_t i; } v; v.f = f;
  uint32_t r = v.i + 0x7fffu + ((v.i >> 16) & 1u);   // round-nearest-even
  return (uint16_t)(r >> 16);
}
__device__ __forceinline__ float sigm(float x){ return 1.0f / (1.0f + __expf(-x)); }
__device__ __forceinline__ float tanh_(float x){
  float t = fminf(fmaxf(2.0f * x, -30.0f), 30.0f);
  float e = __expf(t);
  return (e - 1.0f) / (e + 1.0f);
}

// Split 8 consecutive fp32 into bf16 hi + bf16 lo (residual) fragments.
__device__ __forceinline__ void split8(const float* p, bf16x8& hi8, bf16x8& lo8){
  const float4 a = *(const float4*)p;
  const float4 b = *(const float4*)(p + 4);
  float v[8] = {a.x, a.y, a.z, a.w, b.x, b.y, b.z, b.w};
  #pragma unroll
  for (int j = 0; j < 8; ++j){
    uint16_t h = f2bf(v[j]);
    hi8[j] = (short)h;
    lo8[j] = (short)f2bf(v[j] - bf2f(h));
  }
}

// Persistent LSTM. 128 blocks; block f owns h-cols [8f,8f+8).
// Gate tiles (N=16): tile0 = [H1|H2] (forget|input), tile1 = [H3|H4] (cand|out).
// K split across 4 waves (h:256 each, x:128 each); weights live in VGPRs as
// bf16 hi+lo pairs; A*W done with 3 MFMAs (Ahi*Whi + Alo*Whi + Ahi*Wlo).
// Grid sync: per-block monotone done-flags (128B-padded, store+poll — NO
// same-address atomicAdd, which serialized 128 RMWs at ~200ns each = 25.6us/step).
__global__ void __launch_bounds__(NTHR, 1) lstm_persist(
    const float* __restrict__ x,
    const float* __restrict__ X1, const float* __restrict__ H1, const float* __restrict__ b1,
    const float* __restrict__ X2, const float* __restrict__ H2, const float* __restrict__ b2,
    const float* __restrict__ X3, const float* __restrict__ H3, const float* __restrict__ b3,
    const float* __restrict__ X4, const float* __restrict__ H4, const float* __restrict__ b4,
    float* __restrict__ out, uint16_t* hbhi, uint16_t* hblo, int* done)
{
  __shared__ float part[4][64][36];   // stride 36: quad row-step 4*36 ≡ 16 (mod 32) → 2-way only
  const int tid  = threadIdx.x;
  const int w    = tid >> 6;          // wave 0..3
  const int L    = tid & 63;
  const int c    = L & 15;            // MFMA n / A-row-in-tile
  const int quad = L >> 4;
  const int cc   = c & 7;
  const int f    = blockIdx.x;
  const int colh = f * 8 + cc;        // owned h-column
  const bool hiHalf = (c >= 8);

  const float* W0 = hiHalf ? H2 : H1;
  const float* W1 = hiHalf ? H4 : H3;
  const float* V0 = hiHalf ? X2 : X1;
  const float* V1 = hiHalf ? X4 : X3;
  const float bias0 = (hiHalf ? b2 : b1)[colh];
  const float bias1 = (hiHalf ? b4 : b3)[colh];

  // --- one-time: weight fragments (B layout: n = lane&15, k = quad*8 + j) ---
  bf16x8 BhH0[8], BhL0[8], BhH1[8], BhL1[8];
  #pragma unroll
  for (int kk = 0; kk < 8; ++kk){
    const int kb = w*256 + kk*32 + quad*8;
    bf16x8 h0, l0, h1, l1;
    #pragma unroll
    for (int j = 0; j < 8; ++j){
      float w0 = W0[(size_t)(kb + j)*HD + colh];
      uint16_t a = f2bf(w0); h0[j] = (short)a; l0[j] = (short)f2bf(w0 - bf2f(a));
      float w1 = W1[(size_t)(kb + j)*HD + colh];
      uint16_t b_ = f2bf(w1); h1[j] = (short)b_; l1[j] = (short)f2bf(w1 - bf2f(b_));
    }
    BhH0[kk] = h0; BhL0[kk] = l0; BhH1[kk] = h1; BhL1[kk] = l1;
  }
  bf16x8 BxH0[4], BxL0[4], BxH1[4], BxL1[4];
  #pragma unroll
  for (int kk = 0; kk < 4; ++kk){
    const int kb = w*128 + kk*32 + quad*8;
    bf16x8 h0, l0, h1, l1;
    #pragma unroll
    for (int j = 0; j < 8; ++j){
      float w0 = V0[(size_t)(kb + j)*HD + colh];
      uint16_t a = f2bf(w0); h0[j] = (short)a; l0[j] = (short)f2bf(w0 - bf2f(a));
      float w1 = V1[(size_t)(kb + j)*HD + colh];
      uint16_t b_ = f2bf(w1); h1[j] = (short)b_; l1[j] = (short)f2bf(w1 - bf2f(b_));
    }
    BxH0[kk] = h0; BxL0[kk] = l0; BxH1[kk] = h1; BxL1[kk] = l1;
  }

  float cst[4] = {0.f, 0.f, 0.f, 0.f};

  #pragma unroll 1
  for (int t = 0; t < S_LEN; ++t){
    const int p = t & 1;
    f32x4 acc0[4], acc1[4];
    #pragma unroll
    for (int m = 0; m < 4; ++m){
      acc0[m] = (f32x4){0.f,0.f,0.f,0.f};
      acc1[m] = (f32x4){0.f,0.f,0.f,0.f};
    }

    // ---- x-phase: x_t @ Xcat slice (independent of h; runs before the wait) ----
    #pragma unroll
    for (int kk = 0; kk < 4; ++kk){
      #pragma unroll
      for (int m = 0; m < 4; ++m){
        const float* xp = x + ((size_t)(16*m + c)*S_LEN + t)*IDIM + w*128 + kk*32 + quad*8;
        bf16x8 Ah, Al; split8(xp, Ah, Al);
        acc0[m] = MFMA16(Ah, BxH0[kk], acc0[m], 0, 0, 0);
        acc0[m] = MFMA16(Al, BxH0[kk], acc0[m], 0, 0, 0);
        acc0[m] = MFMA16(Ah, BxL0[kk], acc0[m], 0, 0, 0);
        acc1[m] = MFMA16(Ah, BxH1[kk], acc1[m], 0, 0, 0);
        acc1[m] = MFMA16(Al, BxH1[kk], acc1[m], 0, 0, 0);
        acc1[m] = MFMA16(Ah, BxL1[kk], acc1[m], 0, 0, 0);
      }
    }

    // ---- wait: all blocks must have published h_t (done[b] >= t) ----
    if (t > 0){
      if (tid < NBLK){
        while (__hip_atomic_load(&done[tid*32], __ATOMIC_RELAXED, __HIP_MEMORY_SCOPE_AGENT) < t)
          __builtin_amdgcn_s_sleep(2);
      }
      __syncthreads();
      if (tid == 0) __threadfence();   // acquire: invalidate L1/L2 before reading new h
      __syncthreads();
    }

    // ---- h-phase: h_t @ Hcat slice (pre-split hi/lo bf16, zero conversion) ----
    const uint16_t* hbH = hbhi + (size_t)p * (64*HD);
    const uint16_t* hbL = hblo + (size_t)p * (64*HD);
    #pragma unroll
    for (int kk = 0; kk < 8; ++kk){
      #pragma unroll
      for (int m = 0; m < 4; ++m){
        const size_t off = (size_t)(16*m + c)*HD + w*256 + kk*32 + quad*8;
        bf16x8 Ah = *(const bf16x8*)(hbH + off);
        bf16x8 Al = *(const bf16x8*)(hbL + off);
        acc0[m] = MFMA16(Ah, BhH0[kk], acc0[m], 0, 0, 0);
        acc0[m] = MFMA16(Al, BhH0[kk], acc0[m], 0, 0, 0);
        acc0[m] = MFMA16(Ah, BhL0[kk], acc0[m], 0, 0, 0);
        acc1[m] = MFMA16(Ah, BhH1[kk], acc1[m], 0, 0, 0);
        acc1[m] = MFMA16(Al, BhH1[kk], acc1[m], 0, 0, 0);
        acc1[m] = MFMA16(Ah, BhL1[kk], acc1[m], 0, 0, 0);
      }
    }

    // ---- stash partials (C/D: col = lane&15, row = quad*4 + reg) ----
    #pragma unroll
    for (int m = 0; m < 4; ++m){
      #pragma unroll
      for (int r = 0; r < 4; ++r){
        part[w][16*m + quad*4 + r][c]      = acc0[m][r];
        part[w][16*m + quad*4 + r][16 + c] = acc1[m][r];
      }
    }
    __syncthreads();

    // ---- cross-wave K-reduction; wave w handles batch rows [16w,16w+16) ----
    float g0[4], g1[4];
    #pragma unroll
    for (int r = 0; r < 4; ++r){
      const int row = 16*w + quad*4 + r;
      float a = bias0, b = bias1;
      #pragma unroll
      for (int ww = 0; ww < 4; ++ww){
        a += part[ww][row][c];
        b += part[ww][row][16 + c];
      }
      g0[r] = a; g1[r] = b;
    }

    // ---- gates (lane c<8 holds forget/cand; partner c+8 holds input/output) ----
    uint16_t* hwH = hbhi + (size_t)(p^1) * (64*HD);
    uint16_t* hwL = hblo + (size_t)(p^1) * (64*HD);
    float hv[4];
    #pragma unroll
    for (int r = 0; r < 4; ++r){
      float gf = g0[r];
      float gi = __shfl_xor(g0[r], 8, 64);
      float gc = g1[r];
      float go = __shfl_xor(g1[r], 8, 64);
      float cn = cst[r] * sigm(gf) + sigm(gi) * tanh_(gc);
      cst[r] = cn;
      hv[r] = tanh_(cn) * sigm(go);
    }
    if (!hiHalf){
      #pragma unroll
      for (int r = 0; r < 4; ++r){
        const int batch = 16*w + quad*4 + r;
        __builtin_nontemporal_store(hv[r], &out[(size_t)(batch*S_LEN + t)*HD + colh]);
        uint16_t hh = f2bf(hv[r]);
        hwH[(size_t)batch*HD + colh] = hh;
        hwL[(size_t)batch*HD + colh] = f2bf(hv[r] - bf2f(hh));
      }
    }

    // ---- publish: drain block stores (syncthreads) → L2 writeback → flag store ----
    __syncthreads();
    if (tid == 0){
      __threadfence();   // release: wbl2 so other XCDs see our h hi/lo stores
      __hip_atomic_store(&done[f*32], t + 1, __ATOMIC_RELAXED, __HIP_MEMORY_SCOPE_AGENT);
    }
  }
}

extern "C" void kernel_launch(void* const* d_in, const int* in_sizes, int n_in,
                              void* d_out, int out_size, void* d_ws, size_t ws_size,
                              hipStream_t stream) {
  const float* x  = (const float*)d_in[0];
  const float* X1 = (const float*)d_in[1];
  const float* H1 = (const float*)d_in[2];
  const float* b1 = (const float*)d_in[3];
  const float* X2 = (const float*)d_in[4];
  const float* H2 = (const float*)d_in[5];
  const float* b2 = (const float*)d_in[6];
  const float* X3 = (const float*)d_in[7];
  const float* H3 = (const float*)d_in[8];
  const float* b3 = (const float*)d_in[9];
  const float* X4 = (const float*)d_in[10];
  const float* H4 = (const float*)d_in[11];
  const float* b4 = (const float*)d_in[12];
  float* out = (float*)d_out;

  // ws: hbhi [2][64][1024] bf16 (262144 B) | hblo same | done[128] @128B stride (16384 B)
  uint16_t* hbhi = (uint16_t*)d_ws;
  uint16_t* hblo = (uint16_t*)((char*)d_ws + 262144);
  int* done      = (int*)((char*)d_ws + 524288);
  hipMemsetAsync(d_ws, 0, 524288 + 16384, stream);   // h0 = 0 (hi/lo), flags = 0

  hipLaunchKernelGGL(lstm_persist, dim3(NBLK), dim3(NTHR), 0, stream,
                     x, X1, H1, b1, X2, H2, b2, X3, H3, b3, X4, H4, b4,
                     out, hbhi, hblo, done);
}